// Round 5
// baseline (200.800 us; speedup 1.0000x reference)
//
#include <hip/hip_runtime.h>

static constexpr int KM1     = 1048575;        // sampled elements k=1..KM1 (kk=k-1)
static constexpr int M_S     = 32;
static constexpr int J_IT    = 16;             // iterations per wave, 128 elements each
static constexpr int SPANE   = 128 * J_IT;     // 2048 elements per chunk
static constexpr int NCHUNK  = 512;            // last chunk ragged (2047 elements)
static constexpr int OFF_MAX = 2 * (KM1 - 2);  // max float offset for a pair load

typedef float f32x2 __attribute__((ext_vector_type(2)));

#if __has_builtin(__builtin_amdgcn_logf)
__device__ __forceinline__ float flog2(float x) { return __builtin_amdgcn_logf(x); }
#else
__device__ __forceinline__ float flog2(float x) {
    float r; asm("v_log_f32 %0, %1" : "=v"(r) : "v"(x)); return r;
}
#endif
#if __has_builtin(__builtin_amdgcn_exp2f)
__device__ __forceinline__ float fexp2(float x) { return __builtin_amdgcn_exp2f(x); }
#else
__device__ __forceinline__ float fexp2(float x) {
    float r; asm("v_exp_f32 %0, %1" : "=v"(r) : "v"(x)); return r;
}
#endif

__global__ void zero_out_kernel(float* out) { out[0] = 0.0f; }

// t = exp2( c_ms*(ms1-ms0) + invT*(log2(-log2 u0) - log2(-log2 u1)) )
__device__ __forceinline__ float calc1(f32x2 up, f32x2 mp, float invT, float c_ms) {
    const float a = flog2(-flog2(up.x)) - flog2(-flog2(up.y));
    return fexp2(fmaf(c_ms, mp.y - mp.x, invT * a));
}

struct Raw { f32x2 ua, ub, ma, mb; };

__global__ __launch_bounds__(256, 8) void terp_kernel(
    const float* __restrict__ x,
    const float* __restrict__ ms,
    const float* __restrict__ u,
    float* __restrict__ out)
{
    const int lane  = threadIdx.x & 63;
    const int wave  = threadIdx.x >> 6;
    const int m     = blockIdx.x & 31;   // m fastest -> 32 blocks share one ms chunk
    const int cg    = blockIdx.x >> 5;
    const int chunk = cg * 4 + wave;     // always < NCHUNK (grid sized exactly)

    const float x0 = x[0];
    const float x1 = x[1];
    constexpr float TEMP = 2.5f * 0.9999f;
    constexpr float LN2  = 0.69314718055994530942f;
    const float invT = 1.0f / TEMP;
    const float c_ms = invT / LN2;

    const float* __restrict__ u_row = u + (size_t)m * KM1 * 2;
    const int off0 = chunk * (2 * SPANE) + lane * 4;   // float offset of this lane's pair, iter 0

    float acc = 0.0f;  // log2 units

    auto LOAD = [&](int j, Raw& R) {
        int off = off0 + 256 * j;
        off = min(off, OFF_MAX);
        R.ua = __builtin_nontemporal_load((const f32x2*)(u_row + off));
        R.ub = __builtin_nontemporal_load((const f32x2*)(u_row + off + 2));
        R.ma = *(const f32x2*)(ms + off);
        R.mb = *(const f32x2*)(ms + off + 2);
    };
    auto CALC2 = [&](const Raw& R, float& ta, float& tb) {
        ta = calc1(R.ua, R.ma, invT, c_ms);
        tb = calc1(R.ub, R.mb, invT, c_ms);
    };
    auto CONSUME = [&](float ta, float tb, float taN) {
        const float r = (lane == 0) ? taN : ta;
        const float v = __shfl(r, (lane + 1) & 63);
        const float selfP = (1.0f + ta) * (1.0f + tb);
        const float coupP = fmaf(ta, tb, 1.0f) * fmaf(tb, v, 1.0f);
        acc = fmaf(-2.0f, flog2(selfP), acc + flog2(coupP));
    };

    Raw A, B, C;
    LOAD(0, A); LOAD(1, B); LOAD(2, C);

    // rotate partner for iter 15: first element of next chunk (uniform address)
    const int kkE = min(SPANE * (chunk + 1), KM1 - 1);
    const f32x2 uE = *(const f32x2*)(u_row + 2 * kkE);
    const f32x2 mE = *(const f32x2*)(ms + 2 * kkE);
    const float t_edge = calc1(uE, mE, invT, c_ms);

    float ta0, tb0, ta1, tb1, ta2, tb2;
    CALC2(A, ta0, tb0);

    #pragma unroll
    for (int jt = 0; jt < 7; ++jt) {
        const int j = 2 * jt;
        CALC2(B, ta1, tb1);  LOAD(j + 3, B);  CONSUME(ta0, tb0, ta1);
        CALC2(C, ta2, tb2);  LOAD(j + 4, C);  CONSUME(ta1, tb1, ta2);
        ta0 = ta2; tb0 = tb2;
    }
    // iter 14 (t15 comes from B = raw15)
    CALC2(B, ta1, tb1);
    CONSUME(ta0, tb0, ta1);
    // iter 15
    if (chunk != NCHUNK - 1) {
        CONSUME(ta1, tb1, t_edge);
    } else {
        // ragged: lane63's tb is element k=KM1+1 (doesn't exist) -> mask its terms
        const bool l63 = (lane == 63);
        const float r = (lane == 0) ? t_edge : ta1;
        const float v = __shfl(r, (lane + 1) & 63);
        const float selfP = (1.0f + ta1) * (l63 ? 1.0f : (1.0f + tb1));
        const float coupP = l63 ? 1.0f : (fmaf(ta1, tb1, 1.0f) * fmaf(tb1, v, 1.0f));
        acc = fmaf(-2.0f, flog2(selfP), acc + flog2(coupP));
    }

    // boundary numerators: log2(x0 + x1*t_1) and log2(x0 + x1*t_KM1)
    if (lane == 0 && chunk == 0) {
        const float t1 = calc1(*(const f32x2*)u_row, *(const f32x2*)ms, invT, c_ms);
        acc += flog2(fmaf(x1, t1, x0));
    }
    if (lane == 0 && chunk == NCHUNK - 1) {
        const int offz = 2 * (KM1 - 1);
        const float tz = calc1(*(const f32x2*)(u_row + offz), *(const f32x2*)(ms + offz), invT, c_ms);
        acc += flog2(fmaf(x1, tz, x0));
    }

    // wave reduce (64 lanes)
    #pragma unroll
    for (int off = 32; off >= 1; off >>= 1)
        acc += __shfl_down(acc, off);

    __shared__ float ssum[4];
    if (lane == 0) ssum[wave] = acc;
    __syncthreads();
    if (threadIdx.x == 0) {
        const float bs = ssum[0] + ssum[1] + ssum[2] + ssum[3];
        atomicAdd(out, bs * (-LN2 / (float)M_S));
    }
}

extern "C" void kernel_launch(void* const* d_in, const int* in_sizes, int n_in,
                              void* d_out, int out_size, void* d_ws, size_t ws_size,
                              hipStream_t stream) {
    const float* x  = (const float*)d_in[0];
    const float* ms = (const float*)d_in[1];
    const float* u  = (const float*)d_in[2];
    float* out = (float*)d_out;

    zero_out_kernel<<<1, 1, 0, stream>>>(out);

    const int ncg = NCHUNK / 4;                 // 128 chunk groups (4 waves/block)
    dim3 grid(ncg * 32);                        // 4096 blocks, m fastest
    terp_kernel<<<grid, 256, 0, stream>>>(x, ms, u, out);
}

// Round 6
// 71.621 us; speedup vs baseline: 2.8036x; 2.8036x over previous
//
#include <hip/hip_runtime.h>

static constexpr int KM1     = 1048575;        // sampled elems kk in [0, KM1)
static constexpr int M_S     = 32;
static constexpr int J_IT    = 16;             // iters/wave, 128 elems each
static constexpr int SPANE   = 128 * J_IT;     // 2048 elems per chunk
static constexpr int NCHUNK  = 512;
static constexpr int OFF_MAX = 2 * (KM1 - 2);  // last valid float offset of a pair load
static constexpr int NSLOT   = 64;

typedef float f32x2 __attribute__((ext_vector_type(2)));

#if __has_builtin(__builtin_amdgcn_logf)
__device__ __forceinline__ float flog2(float x) { return __builtin_amdgcn_logf(x); }
#else
__device__ __forceinline__ float flog2(float x) { float r; asm("v_log_f32 %0, %1" : "=v"(r) : "v"(x)); return r; }
#endif
#if __has_builtin(__builtin_amdgcn_exp2f)
__device__ __forceinline__ float fexp2(float x) { return __builtin_amdgcn_exp2f(x); }
#else
__device__ __forceinline__ float fexp2(float x) { float r; asm("v_exp_f32 %0, %1" : "=v"(r) : "v"(x)); return r; }
#endif

struct Raw { f32x2 ua, ub, ma, mb; };

__global__ void zero_ws_kernel(float* ws) { ws[threadIdx.x] = 0.0f; }

__global__ void final_reduce_kernel(const float* __restrict__ ws, float* __restrict__ out) {
    constexpr float LN2 = 0.69314718055994530942f;
    float v = ws[threadIdx.x];   // 64 threads
    #pragma unroll
    for (int off = 32; off >= 1; off >>= 1) v += __shfl_down(v, off);
    if (threadIdx.x == 0) out[0] = v * (-LN2 / (float)M_S);
}

__global__ __launch_bounds__(256, 4) void terp_kernel(
    const float* __restrict__ x,
    const float* __restrict__ ms,
    const float* __restrict__ u,
    float* __restrict__ ws)
{
    const int lane  = threadIdx.x & 63;
    const int wave  = threadIdx.x >> 6;
    const int m     = blockIdx.x & 31;   // m fastest: 32 blocks share one ms window
    const int cg    = blockIdx.x >> 5;
    const int chunk = cg * 4 + wave;

    const float x0 = x[0];
    const float x1 = x[1];
    constexpr float TEMP = 2.5f * 0.9999f;
    const float invT = 1.0f / TEMP;
    const float c_ms = invT / 0.69314718055994530942f;

    const float* __restrict__ u_row = u + (size_t)m * (2 * KM1);
    const float* __restrict__ msp   = ms;
    const int off0 = chunk * (2 * SPANE) + lane * 4;

    float acc = 0.0f;   // log2 units

#define LOADJ(j, R) do { \
        const int off_ = min(off0 + 256 * (j), OFF_MAX); \
        (R).ua = __builtin_nontemporal_load((const f32x2*)(u_row + off_)); \
        (R).ub = __builtin_nontemporal_load((const f32x2*)(u_row + off_ + 2)); \
        (R).ma = *(const f32x2*)(msp + off_); \
        (R).mb = *(const f32x2*)(msp + off_ + 2); \
    } while (0)

#define CALC1(up, mp, t) do { \
        const float a_ = flog2(-flog2((up).x)) - flog2(-flog2((up).y)); \
        (t) = fexp2(fmaf(c_ms, (mp).y - (mp).x, invT * a_)); \
    } while (0)

#define CALC2(R, ta, tb) do { CALC1((R).ua, (R).ma, ta); CALC1((R).ub, (R).mb, tb); } while (0)

#define CONSUME(ta, tb, taN) do { \
        const float r_ = (lane == 0) ? (taN) : (ta); \
        const float v_ = __shfl(r_, (lane + 1) & 63); \
        const float selfP_ = (1.0f + (ta)) * (1.0f + (tb)); \
        const float coupP_ = fmaf((ta), (tb), 1.0f) * fmaf((tb), v_, 1.0f); \
        acc = fmaf(-2.0f, flog2(selfP_), acc + flog2(coupP_)); \
    } while (0)

    Raw R0, R1, R2, R3;
    LOADJ(0, R0); LOADJ(1, R1); LOADJ(2, R2); LOADJ(3, R3);

    // rotate partner for iter 15: first elem of next chunk (wave-uniform)
    const int kkE = min(SPANE * (chunk + 1), KM1 - 1);
    const f32x2 uE = *(const f32x2*)(u_row + 2 * kkE);
    const f32x2 mE = *(const f32x2*)(msp + 2 * kkE);
    float t_edge; CALC1(uE, mE, t_edge);

    float ta_c, tb_c;
    CALC2(R0, ta_c, tb_c);

#define STEP(j, Rn, Rl) do { \
        float ta_n_, tb_n_; CALC2(Rn, ta_n_, tb_n_); \
        if ((j) + 4 < J_IT) LOADJ((j) + 4, Rl); \
        CONSUME(ta_c, tb_c, ta_n_); \
        ta_c = ta_n_; tb_c = tb_n_; \
    } while (0)

    STEP(0, R1, R0);  STEP(1, R2, R1);  STEP(2, R3, R2);  STEP(3, R0, R3);
    STEP(4, R1, R0);  STEP(5, R2, R1);  STEP(6, R3, R2);  STEP(7, R0, R3);
    STEP(8, R1, R0);  STEP(9, R2, R1);  STEP(10, R3, R2); STEP(11, R0, R3);
    STEP(12, R1, R0); STEP(13, R2, R1);

    // j = 14 (t15 from R3 = raw15)
    {
        float ta_n_, tb_n_; CALC2(R3, ta_n_, tb_n_);
        CONSUME(ta_c, tb_c, ta_n_);
        ta_c = ta_n_; tb_c = tb_n_;
    }
    // j = 15
    if (chunk != NCHUNK - 1) {
        CONSUME(ta_c, tb_c, t_edge);
    } else {
        // ragged: lane63's b elem is the phantom (kk = KM1) -> mask its terms
        const bool l63 = (lane == 63);
        const float r_ = (lane == 0) ? t_edge : ta_c;
        const float v_ = __shfl(r_, (lane + 1) & 63);
        const float selfP_ = (1.0f + ta_c) * (l63 ? 1.0f : (1.0f + tb_c));
        const float coupP_ = l63 ? 1.0f : (fmaf(ta_c, tb_c, 1.0f) * fmaf(tb_c, v_, 1.0f));
        acc = fmaf(-2.0f, flog2(selfP_), acc + flog2(coupP_));
    }

    // boundary numerators: log2(x0 + x1*t_first) and log2(x0 + x1*t_last)
    if (lane == 0 && chunk == 0) {
        const f32x2 u0 = *(const f32x2*)u_row, m0 = *(const f32x2*)msp;
        float t1; CALC1(u0, m0, t1);
        acc += flog2(fmaf(x1, t1, x0));
    }
    if (lane == 0 && chunk == NCHUNK - 1) {
        const int offz = 2 * (KM1 - 1);
        const f32x2 uz = *(const f32x2*)(u_row + offz), mz = *(const f32x2*)(msp + offz);
        float tz; CALC1(uz, mz, tz);
        acc += flog2(fmaf(x1, tz, x0));
    }

    // wave reduce
    #pragma unroll
    for (int off = 32; off >= 1; off >>= 1) acc += __shfl_down(acc, off);

    __shared__ float ssum[4];
    if (lane == 0) ssum[wave] = acc;
    __syncthreads();
    if (threadIdx.x == 0)
        atomicAdd(&ws[blockIdx.x & (NSLOT - 1)], ssum[0] + ssum[1] + ssum[2] + ssum[3]);
}

extern "C" void kernel_launch(void* const* d_in, const int* in_sizes, int n_in,
                              void* d_out, int out_size, void* d_ws, size_t ws_size,
                              hipStream_t stream) {
    const float* x  = (const float*)d_in[0];
    const float* ms = (const float*)d_in[1];
    const float* u  = (const float*)d_in[2];

    float* ws = (float*)d_ws;
    zero_ws_kernel<<<1, NSLOT, 0, stream>>>(ws);

    dim3 grid((NCHUNK / 4) * 32);   // 4096 blocks, m fastest
    terp_kernel<<<grid, 256, 0, stream>>>(x, ms, u, ws);

    final_reduce_kernel<<<1, 64, 0, stream>>>(ws, (float*)d_out);
}